// Round 8
// baseline (283.136 us; speedup 1.0000x reference)
//
#include <hip/hip_runtime.h>
#include <stdint.h>

#define BB 32
#define CC 2048
#define NPIX 49
#define KPAD 64
#define K9 18432      // CC*9 (k = tap*2048 + ci, tap-major)
#define ZROWS 2624    // 32*81 interior+halo rows + 32 guard rows (zero)
#define NP 1792       // dense n padded (14*128); nt=13 tile is all-pad -> not computed
#define CONV_SPLITK 4

typedef __bf16 bf16;
typedef __bf16 bf16x2 __attribute__((ext_vector_type(2)));
typedef __bf16 bf16x4 __attribute__((ext_vector_type(4)));
typedef __bf16 bf16x8 __attribute__((ext_vector_type(8)));
typedef float f32x4 __attribute__((ext_vector_type(4)));
typedef uint32_t u32x4 __attribute__((ext_vector_type(4)));

#define MFMA(a,b,c) __builtin_amdgcn_mfma_f32_16x16x32_bf16(a,b,c,0,0,0)
#define GLOAD_LDS(g, l) __builtin_amdgcn_global_load_lds( \
    (const __attribute__((address_space(1))) void*)(g),   \
    (__attribute__((address_space(3))) void*)(l), 16, 0, 0)

// ---------- fused prep: x -> xb [B][C][64] AND xbT [B][64][C] (reads x once) ----------
// 512 blocks = b(32) x cb(16); LDS tile [128 c][49 n] f32, transpose in LDS.
__global__ void prep_fused_kernel(const float* __restrict__ x,
                                  bf16* __restrict__ xb, bf16* __restrict__ xbT) {
    __shared__ float xt[6272];   // 128*49
    const int tid = threadIdx.x;
    const int b = blockIdx.x >> 4, cb = blockIdx.x & 15;
    const float* src = x + ((size_t)(b * 2048 + cb * 128)) * 49;
#pragma unroll
    for (int i = 0; i < 25; i++) {
        int idx = i * 256 + tid;
        if (idx < 6272) xt[idx] = src[idx];
    }
    __syncthreads();
    // xb rows (K padded 49->64 with zeros)
    {
        const int r = tid >> 1, h = tid & 1;
        bf16* dst = xb + ((size_t)(b * 2048 + cb * 128 + r)) * 64 + h * 32;
        const float* row = &xt[r * 49];
#pragma unroll
        for (int v = 0; v < 4; v++) {
            bf16x8 o;
#pragma unroll
            for (int e = 0; e < 8; e++) {
                int n = h * 32 + v * 8 + e;
                o[e] = (bf16)(n < 49 ? row[n] : 0.f);
            }
            *(bf16x8*)(dst + v * 8) = o;
        }
    }
    // xbT rows (n in [0,64), rows >=49 zeroed)
    {
        const int n = tid >> 2, q = tid & 3;
        bf16* dst = xbT + ((size_t)b * 64 + n) * 2048 + cb * 128 + q * 32;
#pragma unroll
        for (int v = 0; v < 4; v++) {
            bf16x8 o;
#pragma unroll
            for (int e = 0; e < 8; e++) {
                int cl = q * 32 + v * 8 + e;
                o[e] = (bf16)(n < 49 ? xt[cl * 49 + n] : 0.f);
            }
            *(bf16x8*)(dst + v * 8) = o;
        }
    }
}

// ---------- prep: conv_w [co][ci][3][3] f32 -> Wr [co][t][ci] bf16 ----------
__global__ void castw_kernel(const float* __restrict__ cw, bf16* __restrict__ Wr) {
    uint32_t t = blockIdx.x * 256u + threadIdx.x;
    uint32_t q = t & 511u, co = t >> 9;
    uint32_t ci0 = q * 4u;
    const float* src = cw + ((size_t)co * 2048u + ci0) * 9u;
    float v[4][9];
#pragma unroll
    for (int c = 0; c < 4; c++)
#pragma unroll
        for (int tt = 0; tt < 9; tt++) v[c][tt] = src[c * 9 + tt];
    bf16* dst = Wr + (size_t)co * K9 + ci0;
#pragma unroll
    for (int tt = 0; tt < 9; tt++) {
        bf16x4 o;
        o[0] = (bf16)v[0][tt]; o[1] = (bf16)v[1][tt];
        o[2] = (bf16)v[2][tt]; o[3] = (bf16)v[3][tt];
        *(bf16x4*)(dst + (size_t)tt * 2048u) = o;
    }
}

// ---------- prep: zero YpT ----------
__global__ void zero_ypt_kernel(u32x4* __restrict__ YpT) {
    YpT[blockIdx.x * 256u + threadIdx.x] = (u32x4){0, 0, 0, 0};
}

// ---------- fused bilinear -> softmax -> Y, LDS-staged K/V tiles (R7, unchanged) ----------
__global__ __launch_bounds__(256, 2) void attn_kernel(
    const bf16* __restrict__ xb, const bf16* __restrict__ xbT, bf16* __restrict__ YpT)
{
    __shared__ __align__(16) char smem[67584];
    bf16* Ktile = (bf16*)smem;                         // [128 d][64 k]   swizzled
    bf16* Vtile = (bf16*)(smem + 16384);               // [64 n][128 d]   swizzled
    bf16 (*Plds)[32][136] = reinterpret_cast<bf16(*)[32][136]>(smem + 32768);
    bf16 (*Tlds)[132] = reinterpret_cast<bf16(*)[132]>(smem);

    const int tid = threadIdx.x;
    const int w = tid >> 6, l = tid & 63;
    const int lhi = l >> 4, llo = l & 15;
    const uint32_t g = blockIdx.x;
    const int xcd = g & 7, inner = g >> 3;
    const int b = xcd + (inner >> 4) * 8;
    const int cblk = inner & 15;
    const int c0 = cblk * 128 + w * 32;
    const bf16* xbB = xb + (size_t)b * CC * KPAD;
    const bf16* xbTB = xbT + (size_t)b * KPAD * CC;

    bf16x8 aQ[2][2];
#pragma unroll
    for (int cf = 0; cf < 2; cf++)
#pragma unroll
        for (int kk = 0; kk < 2; kk++)
            aQ[cf][kk] = *(const bf16x8*)(xbB + (uint32_t)(c0 + cf * 16 + llo) * KPAD + kk * 32 + lhi * 8);

    const uint32_t rowK = tid >> 3;
    const uint32_t srcKoff = (uint32_t)(((tid & 7u) ^ (rowK & 7u)) << 3);
    const bf16* kSrc = xbB + (size_t)rowK * KPAD + srcKoff;
    const uint32_t rowV = tid >> 4;
    const uint32_t srcVoff = (uint32_t)(((tid & 15u) ^ (rowV & 7u)) << 3);
    const bf16* vSrc = xbTB + (size_t)rowV * CC + srcVoff;

    f32x4 accY[2][4];
#pragma unroll
    for (int cf = 0; cf < 2; cf++)
#pragma unroll
        for (int nf = 0; nf < 4; nf++) accY[cf][nf] = (f32x4){0, 0, 0, 0};
    float rowsum[2][4] = {};

    const float kES = -0.029442756956917622f;          // -log2(e)/49

    for (int dt = 0; dt < 16; dt++) {
        const int d0 = dt * 128;
#pragma unroll
        for (int i = 0; i < 4; i++) {
            GLOAD_LDS(kSrc + (size_t)(d0 + i * 32) * KPAD, (char*)Ktile + i * 4096 + tid * 16);
            GLOAD_LDS(vSrc + d0 + (size_t)i * 16 * CC,     (char*)Vtile + i * 4096 + tid * 16);
        }
        __syncthreads();

        f32x4 accS[2][8];
#pragma unroll
        for (int cf = 0; cf < 2; cf++)
#pragma unroll
            for (int df = 0; df < 8; df++) accS[cf][df] = (f32x4){0, 0, 0, 0};
#pragma unroll
        for (int kk = 0; kk < 2; kk++) {
#pragma unroll
            for (int df = 0; df < 8; df++) {
                uint32_t r = (uint32_t)(df * 16 + llo);
                bf16x8 bK = *(const bf16x8*)((const char*)Ktile + r * 128u +
                                             ((((uint32_t)(kk * 4 + lhi)) ^ (r & 7u)) << 4));
                accS[0][df] = MFMA(aQ[0][kk], bK, accS[0][df]);
                accS[1][df] = MFMA(aQ[1][kk], bK, accS[1][df]);
            }
        }
#pragma unroll
        for (int cf = 0; cf < 2; cf++)
#pragma unroll
            for (int df = 0; df < 8; df++)
#pragma unroll
                for (int r = 0; r < 4; r++) {
                    float p = __builtin_amdgcn_exp2f(accS[cf][df][r] * kES);
                    rowsum[cf][r] += p;
                    Plds[w][cf * 16 + lhi * 4 + r][df * 16 + llo] = (bf16)p;
                }
#pragma unroll
        for (int kk2 = 0; kk2 < 4; kk2++) {
            bf16x8 aP[2];
#pragma unroll
            for (int cf = 0; cf < 2; cf++)
                aP[cf] = *(const bf16x8*)&Plds[w][cf * 16 + llo][kk2 * 32 + lhi * 8];
#pragma unroll
            for (int nf = 0; nf < 4; nf++) {
                uint32_t r = (uint32_t)(nf * 16 + llo);
                bf16x8 bV = *(const bf16x8*)((const char*)Vtile + r * 256u +
                                             ((((uint32_t)(kk2 * 4 + lhi)) ^ (r & 7u)) << 4));
                accY[0][nf] = MFMA(aP[0], bV, accY[0][nf]);
                accY[1][nf] = MFMA(aP[1], bV, accY[1][nf]);
            }
        }
        __syncthreads();
    }
#pragma unroll
    for (int cf = 0; cf < 2; cf++)
#pragma unroll
        for (int r = 0; r < 4; r++) {
            float s = rowsum[cf][r];
            s += __shfl_xor(s, 1);
            s += __shfl_xor(s, 2);
            s += __shfl_xor(s, 4);
            s += __shfl_xor(s, 8);
            rowsum[cf][r] = 1.0f / s;
        }
    __syncthreads();
#pragma unroll
    for (int cf = 0; cf < 2; cf++)
#pragma unroll
        for (int nf = 0; nf < 4; nf++)
#pragma unroll
            for (int r = 0; r < 4; r++) {
                int n = nf * 16 + llo;
                int cl = w * 32 + cf * 16 + lhi * 4 + r;
                Tlds[n][cl] = (bf16)(accY[cf][nf][r] * rowsum[cf][r]);
            }
    __syncthreads();
#pragma unroll
    for (int rr = 0; rr < 13; rr++) {
        int row = rr * 4 + (tid >> 6);
        if (row < NPIX) {
            int i = row / 7, j = row % 7;
            int sp = (i + 1) * 9 + (j + 1);
            int col2 = tid & 63;
            uint32_t val = *(const uint32_t*)&Tlds[row][col2 * 2];
            *(uint32_t*)(YpT + ((size_t)b * 81 + sp) * CC + cblk * 128 + col2 * 2) = val;
        }
    }
}

// ---------- direct conv GEMM: M=2048(co), N=13x128 live tiles, K=18432, splitK=4 ----------
// 832 blocks = 8 xcd x (8 (z,mt) x 13 nt): 3.25 blocks/CU for barrier-drain hiding.
__global__ __launch_bounds__(512, 4) void conv_kernel(
    const bf16* __restrict__ Wr, const bf16* __restrict__ YpT, float* __restrict__ partials)
{
    __shared__ bf16 Asub[128 * 64];
    __shared__ bf16 Bsub[128 * 64];
    const int tid = threadIdx.x;
    const int w = tid >> 6, l = tid & 63;
    const int lhi = l >> 4, llo = l & 15;
    const int wm = w >> 2, wn = w & 3;

    uint32_t g = blockIdx.x;
    uint32_t xcd = g & 7u, inner = g >> 3;       // inner in [0,104)
    uint32_t pairIdx = xcd * 8u + inner / 13u;   // [0,64): (z,mt) grouped per XCD
    uint32_t nt = inner % 13u;
    uint32_t z = pairIdx >> 4, mt = pairIdx & 15u;

    uint32_t kb16 = tid & 7u;
    uint32_t row0 = tid >> 3;
    uint32_t srcK = (kb16 ^ (row0 & 7u)) << 3;

    const bf16* gaBase[2];
    const bf16* gbBase[2];
#pragma unroll
    for (int i = 0; i < 2; i++) {
        uint32_t row = row0 + (uint32_t)i * 64u;
        gaBase[i] = Wr + (size_t)(mt * 128u + row) * K9 + (size_t)z * 4608u + srcK;
        uint32_t n = nt * 128u + row;
        uint32_t rowIdx;
        if (n < 1568u) {
            uint32_t b = n / 49u, p = n % 49u;
            uint32_t i2 = p / 7u, j2 = p % 7u;
            rowIdx = b * 81u + (i2 + 1u) * 9u + (j2 + 1u);
        } else rowIdx = 2602u;
        gbBase[i] = YpT + (size_t)rowIdx * 2048u + srcK;
    }

    f32x4 acc[4][2];
#pragma unroll
    for (int fm = 0; fm < 4; fm++)
#pragma unroll
        for (int fn = 0; fn < 2; fn++) acc[fm][fn] = (f32x4){0, 0, 0, 0};

    for (int ktl = 0; ktl < 72; ktl++) {
        uint32_t kt = z * 72u + (uint32_t)ktl;
        uint32_t tap = kt >> 5, ci0 = (kt & 31u) << 6;
        int tapoff = (int)(tap / 3u) * 9 + (int)(tap % 3u) - 10;
        uint32_t kbA = (uint32_t)ktl * 64u;
#pragma unroll
        for (int i = 0; i < 2; i++) {
            GLOAD_LDS(gaBase[i] + kbA, (char*)Asub + i * 8192 + tid * 16);
            GLOAD_LDS(gbBase[i] + (int)ci0 + tapoff * 2048, (char*)Bsub + i * 8192 + tid * 16);
        }
        __syncthreads();
#pragma unroll
        for (int kk = 0; kk < 2; kk++) {
            bf16x8 af[4], bfr[2];
#pragma unroll
            for (int f = 0; f < 4; f++) {
                uint32_t r = (uint32_t)(wm * 64 + f * 16 + llo);
                uint32_t bo = r * 128u + ((((uint32_t)(kk * 4 + lhi)) ^ (r & 7u)) << 4);
                af[f] = *(const bf16x8*)((const char*)Asub + bo);
            }
#pragma unroll
            for (int f = 0; f < 2; f++) {
                uint32_t r = (uint32_t)(wn * 32 + f * 16 + llo);
                uint32_t bo = r * 128u + ((((uint32_t)(kk * 4 + lhi)) ^ (r & 7u)) << 4);
                bfr[f] = *(const bf16x8*)((const char*)Bsub + bo);
            }
#pragma unroll
            for (int fm = 0; fm < 4; fm++)
#pragma unroll
                for (int fn = 0; fn < 2; fn++)
                    acc[fm][fn] = MFMA(af[fm], bfr[fn], acc[fm][fn]);
        }
        __syncthreads();
    }
    float* pz = partials + (size_t)z * 2048u * NP;
    uint32_t co0 = mt * 128u + (uint32_t)(wm * 64 + lhi * 4);
    uint32_t n0 = nt * 128u + (uint32_t)(wn * 32 + llo);
#pragma unroll
    for (int fm = 0; fm < 4; fm++)
#pragma unroll
        for (int fn = 0; fn < 2; fn++)
#pragma unroll
            for (int r = 0; r < 4; r++)
                pz[(size_t)(co0 + fm * 16u + r) * NP + (n0 + fn * 16u)] = acc[fm][fn][r];
}

// ---------- reduce: out = sum_z partials + bias + residual ----------
__global__ void reduce_kernel(const float* __restrict__ partials, const float* __restrict__ x,
                              const float* __restrict__ cb, float* __restrict__ out)
{
    uint32_t idx = blockIdx.x * 256u + threadIdx.x;
    uint32_t p = idx % 49u;
    uint32_t c = (idx / 49u) & 2047u;
    uint32_t b = idx / (49u * 2048u);
    uint32_t n = b * 49u + p;
    size_t base = (size_t)c * NP + n;
    float s = cb[c] + x[idx];
#pragma unroll
    for (int zz = 0; zz < CONV_SPLITK; zz++) s += partials[(size_t)zz * 2048u * NP + base];
    out[idx] = s;
}

extern "C" void kernel_launch(void* const* d_in, const int* in_sizes, int n_in,
                              void* d_out, int out_size, void* d_ws, size_t ws_size,
                              hipStream_t stream) {
    (void)in_sizes; (void)n_in; (void)out_size; (void)ws_size;
    const float* x = (const float*)d_in[0];
    const float* cw = (const float*)d_in[1];
    const float* cb = (const float*)d_in[2];
    float* out = (float*)d_out;
    char* ws = (char*)d_ws;

    bf16* xb   = (bf16*)(ws);                    //   8,388,608 B
    bf16* xbT  = (bf16*)(ws + 8388608);          //   8,388,608 B
    bf16* Wr   = (bf16*)(ws + 16777216);         //  75,497,472 B
    bf16* YpT  = (bf16*)(ws + 92274688);         //  10,747,904 B
    float* partials = (float*)(ws + 103022592);  //  58,720,256 B (total 161,742,848)

    prep_fused_kernel<<<512, 256, 0, stream>>>(x, xb, xbT);
    castw_kernel<<<4096, 256, 0, stream>>>(cw, Wr);
    zero_ypt_kernel<<<2624, 256, 0, stream>>>((u32x4*)YpT);
    attn_kernel<<<512, 256, 0, stream>>>(xb, xbT, YpT);
    conv_kernel<<<832, 512, 0, stream>>>(Wr, YpT, partials);
    reduce_kernel<<<12544, 256, 0, stream>>>(partials, x, cb, out);
}

// Round 9
// 256.149 us; speedup vs baseline: 1.1054x; 1.1054x over previous
//
#include <hip/hip_runtime.h>
#include <stdint.h>

#define BB 32
#define CC 2048
#define NPIX 49
#define KPAD 64
#define K9 18432      // CC*9 (k = tap*2048 + ci, tap-major)
#define ZROWS 2624    // 32*81 interior+halo rows + 32 guard rows (zero)
#define NP 1792       // dense n padded (14*128)
#define CONV_SPLITK 4

typedef __bf16 bf16;
typedef __bf16 bf16x2 __attribute__((ext_vector_type(2)));
typedef __bf16 bf16x4 __attribute__((ext_vector_type(4)));
typedef __bf16 bf16x8 __attribute__((ext_vector_type(8)));
typedef float f32x4 __attribute__((ext_vector_type(4)));
typedef uint32_t u32x4 __attribute__((ext_vector_type(4)));

#define MFMA(a,b,c) __builtin_amdgcn_mfma_f32_16x16x32_bf16(a,b,c,0,0,0)
#define GLOAD_LDS(g, l) __builtin_amdgcn_global_load_lds( \
    (const __attribute__((address_space(1))) void*)(g),   \
    (__attribute__((address_space(3))) void*)(l), 16, 0, 0)

// ---------- fused prep: x -> xb [B][C][64] AND xbT [B][64][C] (reads x once) ----------
__global__ void prep_fused_kernel(const float* __restrict__ x,
                                  bf16* __restrict__ xb, bf16* __restrict__ xbT) {
    __shared__ float xt[6272];   // 128*49
    const int tid = threadIdx.x;
    const int b = blockIdx.x >> 4, cb = blockIdx.x & 15;
    const float* src = x + ((size_t)(b * 2048 + cb * 128)) * 49;
#pragma unroll
    for (int i = 0; i < 25; i++) {
        int idx = i * 256 + tid;
        if (idx < 6272) xt[idx] = src[idx];
    }
    __syncthreads();
    {
        const int r = tid >> 1, h = tid & 1;
        bf16* dst = xb + ((size_t)(b * 2048 + cb * 128 + r)) * 64 + h * 32;
        const float* row = &xt[r * 49];
#pragma unroll
        for (int v = 0; v < 4; v++) {
            bf16x8 o;
#pragma unroll
            for (int e = 0; e < 8; e++) {
                int n = h * 32 + v * 8 + e;
                o[e] = (bf16)(n < 49 ? row[n] : 0.f);
            }
            *(bf16x8*)(dst + v * 8) = o;
        }
    }
    {
        const int n = tid >> 2, q = tid & 3;
        bf16* dst = xbT + ((size_t)b * 64 + n) * 2048 + cb * 128 + q * 32;
#pragma unroll
        for (int v = 0; v < 4; v++) {
            bf16x8 o;
#pragma unroll
            for (int e = 0; e < 8; e++) {
                int cl = q * 32 + v * 8 + e;
                o[e] = (bf16)(n < 49 ? xt[cl * 49 + n] : 0.f);
            }
            *(bf16x8*)(dst + v * 8) = o;
        }
    }
}

// ---------- prep: conv_w [co][ci][3][3] f32 -> Wr [co][t][ci] bf16 ----------
__global__ void castw_kernel(const float* __restrict__ cw, bf16* __restrict__ Wr) {
    uint32_t t = blockIdx.x * 256u + threadIdx.x;
    uint32_t q = t & 511u, co = t >> 9;
    uint32_t ci0 = q * 4u;
    const float* src = cw + ((size_t)co * 2048u + ci0) * 9u;
    float v[4][9];
#pragma unroll
    for (int c = 0; c < 4; c++)
#pragma unroll
        for (int tt = 0; tt < 9; tt++) v[c][tt] = src[c * 9 + tt];
    bf16* dst = Wr + (size_t)co * K9 + ci0;
#pragma unroll
    for (int tt = 0; tt < 9; tt++) {
        bf16x4 o;
        o[0] = (bf16)v[0][tt]; o[1] = (bf16)v[1][tt];
        o[2] = (bf16)v[2][tt]; o[3] = (bf16)v[3][tt];
        *(bf16x4*)(dst + (size_t)tt * 2048u) = o;
    }
}

// ---------- prep: zero YpT ----------
__global__ void zero_ypt_kernel(u32x4* __restrict__ YpT) {
    YpT[blockIdx.x * 256u + threadIdx.x] = (u32x4){0, 0, 0, 0};
}

// ---------- fused bilinear -> softmax -> Y, LDS-staged K/V tiles (R7, unchanged) ----------
__global__ __launch_bounds__(256, 2) void attn_kernel(
    const bf16* __restrict__ xb, const bf16* __restrict__ xbT, bf16* __restrict__ YpT)
{
    __shared__ __align__(16) char smem[67584];
    bf16* Ktile = (bf16*)smem;
    bf16* Vtile = (bf16*)(smem + 16384);
    bf16 (*Plds)[32][136] = reinterpret_cast<bf16(*)[32][136]>(smem + 32768);
    bf16 (*Tlds)[132] = reinterpret_cast<bf16(*)[132]>(smem);

    const int tid = threadIdx.x;
    const int w = tid >> 6, l = tid & 63;
    const int lhi = l >> 4, llo = l & 15;
    const uint32_t g = blockIdx.x;
    const int xcd = g & 7, inner = g >> 3;
    const int b = xcd + (inner >> 4) * 8;
    const int cblk = inner & 15;
    const int c0 = cblk * 128 + w * 32;
    const bf16* xbB = xb + (size_t)b * CC * KPAD;
    const bf16* xbTB = xbT + (size_t)b * KPAD * CC;

    bf16x8 aQ[2][2];
#pragma unroll
    for (int cf = 0; cf < 2; cf++)
#pragma unroll
        for (int kk = 0; kk < 2; kk++)
            aQ[cf][kk] = *(const bf16x8*)(xbB + (uint32_t)(c0 + cf * 16 + llo) * KPAD + kk * 32 + lhi * 8);

    const uint32_t rowK = tid >> 3;
    const uint32_t srcKoff = (uint32_t)(((tid & 7u) ^ (rowK & 7u)) << 3);
    const bf16* kSrc = xbB + (size_t)rowK * KPAD + srcKoff;
    const uint32_t rowV = tid >> 4;
    const uint32_t srcVoff = (uint32_t)(((tid & 15u) ^ (rowV & 7u)) << 3);
    const bf16* vSrc = xbTB + (size_t)rowV * CC + srcVoff;

    f32x4 accY[2][4];
#pragma unroll
    for (int cf = 0; cf < 2; cf++)
#pragma unroll
        for (int nf = 0; nf < 4; nf++) accY[cf][nf] = (f32x4){0, 0, 0, 0};
    float rowsum[2][4] = {};

    const float kES = -0.029442756956917622f;

    for (int dt = 0; dt < 16; dt++) {
        const int d0 = dt * 128;
#pragma unroll
        for (int i = 0; i < 4; i++) {
            GLOAD_LDS(kSrc + (size_t)(d0 + i * 32) * KPAD, (char*)Ktile + i * 4096 + tid * 16);
            GLOAD_LDS(vSrc + d0 + (size_t)i * 16 * CC,     (char*)Vtile + i * 4096 + tid * 16);
        }
        __syncthreads();

        f32x4 accS[2][8];
#pragma unroll
        for (int cf = 0; cf < 2; cf++)
#pragma unroll
            for (int df = 0; df < 8; df++) accS[cf][df] = (f32x4){0, 0, 0, 0};
#pragma unroll
        for (int kk = 0; kk < 2; kk++) {
#pragma unroll
            for (int df = 0; df < 8; df++) {
                uint32_t r = (uint32_t)(df * 16 + llo);
                bf16x8 bK = *(const bf16x8*)((const char*)Ktile + r * 128u +
                                             ((((uint32_t)(kk * 4 + lhi)) ^ (r & 7u)) << 4));
                accS[0][df] = MFMA(aQ[0][kk], bK, accS[0][df]);
                accS[1][df] = MFMA(aQ[1][kk], bK, accS[1][df]);
            }
        }
#pragma unroll
        for (int cf = 0; cf < 2; cf++)
#pragma unroll
            for (int df = 0; df < 8; df++)
#pragma unroll
                for (int r = 0; r < 4; r++) {
                    float p = __builtin_amdgcn_exp2f(accS[cf][df][r] * kES);
                    rowsum[cf][r] += p;
                    Plds[w][cf * 16 + lhi * 4 + r][df * 16 + llo] = (bf16)p;
                }
#pragma unroll
        for (int kk2 = 0; kk2 < 4; kk2++) {
            bf16x8 aP[2];
#pragma unroll
            for (int cf = 0; cf < 2; cf++)
                aP[cf] = *(const bf16x8*)&Plds[w][cf * 16 + llo][kk2 * 32 + lhi * 8];
#pragma unroll
            for (int nf = 0; nf < 4; nf++) {
                uint32_t r = (uint32_t)(nf * 16 + llo);
                bf16x8 bV = *(const bf16x8*)((const char*)Vtile + r * 256u +
                                             ((((uint32_t)(kk2 * 4 + lhi)) ^ (r & 7u)) << 4));
                accY[0][nf] = MFMA(aP[0], bV, accY[0][nf]);
                accY[1][nf] = MFMA(aP[1], bV, accY[1][nf]);
            }
        }
        __syncthreads();
    }
#pragma unroll
    for (int cf = 0; cf < 2; cf++)
#pragma unroll
        for (int r = 0; r < 4; r++) {
            float s = rowsum[cf][r];
            s += __shfl_xor(s, 1);
            s += __shfl_xor(s, 2);
            s += __shfl_xor(s, 4);
            s += __shfl_xor(s, 8);
            rowsum[cf][r] = 1.0f / s;
        }
    __syncthreads();
#pragma unroll
    for (int cf = 0; cf < 2; cf++)
#pragma unroll
        for (int nf = 0; nf < 4; nf++)
#pragma unroll
            for (int r = 0; r < 4; r++) {
                int n = nf * 16 + llo;
                int cl = w * 32 + cf * 16 + lhi * 4 + r;
                Tlds[n][cl] = (bf16)(accY[cf][nf][r] * rowsum[cf][r]);
            }
    __syncthreads();
#pragma unroll
    for (int rr = 0; rr < 13; rr++) {
        int row = rr * 4 + (tid >> 6);
        if (row < NPIX) {
            int i = row / 7, j = row % 7;
            int sp = (i + 1) * 9 + (j + 1);
            int col2 = tid & 63;
            uint32_t val = *(const uint32_t*)&Tlds[row][col2 * 2];
            *(uint32_t*)(YpT + ((size_t)b * 81 + sp) * CC + cblk * 128 + col2 * 2) = val;
        }
    }
}

// ---------- conv GEMM: 256x256 tile, BK=64, counted-vmcnt double-buffer pipeline ----------
// 224 blocks = z4 x mt8 x nt7, 1 block/CU, 128KB dynamic LDS.
// buf0: A@0 B@32768; buf1: A@65536 B@98304. 8 gload_lds/thread per K-tile.
#define CONV_BAR() do { __builtin_amdgcn_sched_barrier(0); \
    __builtin_amdgcn_s_barrier(); __builtin_amdgcn_sched_barrier(0); } while (0)
#define CONV_VMW(n) asm volatile("s_waitcnt vmcnt(" #n ")" ::: "memory")

#define CONV_STAGE(bufOff, t) do {                                             \
    uint32_t ktg_ = z * 72u + (uint32_t)(t);                                   \
    uint32_t tap_ = ktg_ >> 5, ci0_ = (ktg_ & 31u) << 6;                       \
    int tapoff_ = (int)(tap_ / 3u) * 9 + (int)(tap_ % 3u) - 10;                \
    _Pragma("unroll")                                                          \
    for (int i_ = 0; i_ < 4; i_++) {                                           \
        GLOAD_LDS(gaBase[i_] + (uint32_t)(t) * 64u,                            \
                  smem + (bufOff) + i_ * 8192 + tid * 16);                     \
        GLOAD_LDS(gbBase[i_] + (int)ci0_ + tapoff_ * 2048,                     \
                  smem + (bufOff) + 32768 + i_ * 8192 + tid * 16);             \
    }                                                                          \
} while (0)

#define CONV_COMPUTE(aOff, bOff) do {                                          \
    __builtin_amdgcn_s_setprio(1);                                             \
    _Pragma("unroll")                                                          \
    for (int kk = 0; kk < 2; kk++) {                                           \
        bf16x8 af[8]; bf16x8 bfr[4];                                           \
        _Pragma("unroll")                                                      \
        for (int f = 0; f < 8; f++) {                                          \
            uint32_t r_ = (uint32_t)(wm * 128 + f * 16 + llo);                 \
            af[f] = *(const bf16x8*)(smem + (aOff) + r_ * 128u +               \
                     ((((uint32_t)(kk * 4 + lhi)) ^ (r_ & 7u)) << 4));         \
        }                                                                      \
        _Pragma("unroll")                                                      \
        for (int f = 0; f < 4; f++) {                                          \
            uint32_t r_ = (uint32_t)(wn * 64 + f * 16 + llo);                  \
            bfr[f] = *(const bf16x8*)(smem + (bOff) + r_ * 128u +              \
                     ((((uint32_t)(kk * 4 + lhi)) ^ (r_ & 7u)) << 4));         \
        }                                                                      \
        _Pragma("unroll")                                                      \
        for (int fm = 0; fm < 8; fm++)                                         \
            _Pragma("unroll")                                                  \
            for (int fn = 0; fn < 4; fn++)                                     \
                acc[fm][fn] = MFMA(af[fm], bfr[fn], acc[fm][fn]);              \
    }                                                                          \
    __builtin_amdgcn_s_setprio(0);                                             \
} while (0)

__global__ __launch_bounds__(512, 2) void conv_kernel(
    const bf16* __restrict__ Wr, const bf16* __restrict__ YpT, float* __restrict__ partials)
{
    extern __shared__ __align__(16) char smem[];
    const int tid = threadIdx.x;
    const int w = tid >> 6, l = tid & 63;
    const int lhi = l >> 4, llo = l & 15;
    const int wm = w >> 2, wn = w & 3;           // wave owns 128co x 64n

    uint32_t g = blockIdx.x;
    uint32_t xcd = g & 7u, inner = g >> 3;       // inner in [0,28)
    uint32_t pairIdx = xcd * 4u + inner / 7u;    // [0,32): (z,mt) grouped per XCD
    uint32_t nt = inner % 7u;
    uint32_t z = pairIdx >> 3, mt = pairIdx & 7u;

    uint32_t row0 = tid >> 3;                    // [0,64)
    uint32_t srcK = ((tid & 7u) ^ (row0 & 7u)) << 3;

    const bf16* gaBase[4];
    const bf16* gbBase[4];
#pragma unroll
    for (int i = 0; i < 4; i++) {
        uint32_t row = row0 + (uint32_t)i * 64u;
        gaBase[i] = Wr + (size_t)(mt * 256u + row) * K9 + (size_t)z * 4608u + srcK;
        uint32_t n = nt * 256u + row;
        uint32_t rowIdx;
        if (n < 1568u) {
            uint32_t b = n / 49u, p = n % 49u;
            uint32_t i2 = p / 7u, j2 = p % 7u;
            rowIdx = b * 81u + (i2 + 1u) * 9u + (j2 + 1u);
        } else rowIdx = 2602u;
        gbBase[i] = YpT + (size_t)rowIdx * 2048u + srcK;
    }

    f32x4 acc[8][4];
#pragma unroll
    for (int fm = 0; fm < 8; fm++)
#pragma unroll
        for (int fn = 0; fn < 4; fn++) acc[fm][fn] = (f32x4){0, 0, 0, 0};

    // prologue: stage K-tiles 0,1
    CONV_STAGE(0, 0);
    CONV_STAGE(65536, 1);

    for (int it = 0; it < 35; ++it) {
        const int t0 = it * 2;
        CONV_VMW(8);               // tile t0 complete (tile t0+1 still in flight)
        CONV_BAR();
        CONV_COMPUTE(0, 32768);
        CONV_BAR();                // all waves done reading buf0
        CONV_STAGE(0, t0 + 2);
        CONV_VMW(8);               // tile t0+1 complete
        CONV_BAR();
        CONV_COMPUTE(65536, 98304);
        CONV_BAR();
        CONV_STAGE(65536, t0 + 3);
    }
    // epilogue: tiles 70, 71 (no further staging)
    CONV_VMW(8);
    CONV_BAR();
    CONV_COMPUTE(0, 32768);
    CONV_VMW(0);
    CONV_BAR();
    CONV_COMPUTE(65536, 98304);

    float* pz = partials + (size_t)z * 2048u * NP;
    uint32_t co0 = mt * 256u + (uint32_t)(wm * 128 + lhi * 4);
    uint32_t n0 = nt * 256u + (uint32_t)(wn * 64 + llo);
#pragma unroll
    for (int fm = 0; fm < 8; fm++)
#pragma unroll
        for (int fn = 0; fn < 4; fn++)
#pragma unroll
            for (int r = 0; r < 4; r++)
                pz[(size_t)(co0 + fm * 16u + r) * NP + (n0 + fn * 16u)] = acc[fm][fn][r];
}

// ---------- reduce: out = sum_z partials + bias + residual ----------
__global__ void reduce_kernel(const float* __restrict__ partials, const float* __restrict__ x,
                              const float* __restrict__ cb, float* __restrict__ out)
{
    uint32_t idx = blockIdx.x * 256u + threadIdx.x;
    uint32_t p = idx % 49u;
    uint32_t c = (idx / 49u) & 2047u;
    uint32_t b = idx / (49u * 2048u);
    uint32_t n = b * 49u + p;
    size_t base = (size_t)c * NP + n;
    float s = cb[c] + x[idx];
#pragma unroll
    for (int zz = 0; zz < CONV_SPLITK; zz++) s += partials[(size_t)zz * 2048u * NP + base];
    out[idx] = s;
}

extern "C" void kernel_launch(void* const* d_in, const int* in_sizes, int n_in,
                              void* d_out, int out_size, void* d_ws, size_t ws_size,
                              hipStream_t stream) {
    (void)in_sizes; (void)n_in; (void)out_size; (void)ws_size;
    const float* x = (const float*)d_in[0];
    const float* cw = (const float*)d_in[1];
    const float* cb = (const float*)d_in[2];
    float* out = (float*)d_out;
    char* ws = (char*)d_ws;

    bf16* xb   = (bf16*)(ws);                    //   8,388,608 B
    bf16* xbT  = (bf16*)(ws + 8388608);          //   8,388,608 B
    bf16* Wr   = (bf16*)(ws + 16777216);         //  75,497,472 B
    bf16* YpT  = (bf16*)(ws + 92274688);         //  10,747,904 B
    float* partials = (float*)(ws + 103022592);  //  58,720,256 B (total 161,742,848)

    hipFuncSetAttribute((const void*)conv_kernel,
                        hipFuncAttributeMaxDynamicSharedMemorySize, 131072);

    prep_fused_kernel<<<512, 256, 0, stream>>>(x, xb, xbT);
    castw_kernel<<<4096, 256, 0, stream>>>(cw, Wr);
    zero_ypt_kernel<<<2624, 256, 0, stream>>>((u32x4*)YpT);
    attn_kernel<<<512, 256, 0, stream>>>(xb, xbT, YpT);
    conv_kernel<<<224, 512, 131072, stream>>>(Wr, YpT, partials);
    reduce_kernel<<<12544, 256, 0, stream>>>(partials, x, cb, out);
}

// Round 10
// 242.903 us; speedup vs baseline: 1.1656x; 1.0545x over previous
//
#include <hip/hip_runtime.h>
#include <stdint.h>

#define BB 32
#define CC 2048
#define NPIX 49
#define KPAD 64
#define K9 18432      // CC*9 (k = tap*2048 + ci, tap-major)
#define ZROWS 2624    // 32*81 interior+halo rows + 32 guard rows (zero)
#define NP 1792       // dense n padded (14*128)
#define CONV_SPLITK 4

typedef __bf16 bf16;
typedef __bf16 bf16x2 __attribute__((ext_vector_type(2)));
typedef __bf16 bf16x4 __attribute__((ext_vector_type(4)));
typedef __bf16 bf16x8 __attribute__((ext_vector_type(8)));
typedef float f32x4 __attribute__((ext_vector_type(4)));
typedef uint32_t u32x4 __attribute__((ext_vector_type(4)));

#define MFMA(a,b,c) __builtin_amdgcn_mfma_f32_16x16x32_bf16(a,b,c,0,0,0)
#define GLOAD_LDS(g, l) __builtin_amdgcn_global_load_lds( \
    (const __attribute__((address_space(1))) void*)(g),   \
    (__attribute__((address_space(3))) void*)(l), 16, 0, 0)

// ---------- fused prep: x -> xb [B][C][64] AND xbT [B][64][C] (reads x once) ----------
__global__ void prep_fused_kernel(const float* __restrict__ x,
                                  bf16* __restrict__ xb, bf16* __restrict__ xbT) {
    __shared__ float xt[6272];   // 128*49
    const int tid = threadIdx.x;
    const int b = blockIdx.x >> 4, cb = blockIdx.x & 15;
    const float* src = x + ((size_t)(b * 2048 + cb * 128)) * 49;
#pragma unroll
    for (int i = 0; i < 25; i++) {
        int idx = i * 256 + tid;
        if (idx < 6272) xt[idx] = src[idx];
    }
    __syncthreads();
    {
        const int r = tid >> 1, h = tid & 1;
        bf16* dst = xb + ((size_t)(b * 2048 + cb * 128 + r)) * 64 + h * 32;
        const float* row = &xt[r * 49];
#pragma unroll
        for (int v = 0; v < 4; v++) {
            bf16x8 o;
#pragma unroll
            for (int e = 0; e < 8; e++) {
                int n = h * 32 + v * 8 + e;
                o[e] = (bf16)(n < 49 ? row[n] : 0.f);
            }
            *(bf16x8*)(dst + v * 8) = o;
        }
    }
    {
        const int n = tid >> 2, q = tid & 3;
        bf16* dst = xbT + ((size_t)b * 64 + n) * 2048 + cb * 128 + q * 32;
#pragma unroll
        for (int v = 0; v < 4; v++) {
            bf16x8 o;
#pragma unroll
            for (int e = 0; e < 8; e++) {
                int cl = q * 32 + v * 8 + e;
                o[e] = (bf16)(n < 49 ? xt[cl * 49 + n] : 0.f);
            }
            *(bf16x8*)(dst + v * 8) = o;
        }
    }
}

// ---------- prep: conv_w [co][ci][3][3] f32 -> Wr [co][t][ci] bf16 ----------
__global__ void castw_kernel(const float* __restrict__ cw, bf16* __restrict__ Wr) {
    uint32_t t = blockIdx.x * 256u + threadIdx.x;
    uint32_t q = t & 511u, co = t >> 9;
    uint32_t ci0 = q * 4u;
    const float* src = cw + ((size_t)co * 2048u + ci0) * 9u;
    float v[4][9];
#pragma unroll
    for (int c = 0; c < 4; c++)
#pragma unroll
        for (int tt = 0; tt < 9; tt++) v[c][tt] = src[c * 9 + tt];
    bf16* dst = Wr + (size_t)co * K9 + ci0;
#pragma unroll
    for (int tt = 0; tt < 9; tt++) {
        bf16x4 o;
        o[0] = (bf16)v[0][tt]; o[1] = (bf16)v[1][tt];
        o[2] = (bf16)v[2][tt]; o[3] = (bf16)v[3][tt];
        *(bf16x4*)(dst + (size_t)tt * 2048u) = o;
    }
}

// ---------- prep: zero YpT ----------
__global__ void zero_ypt_kernel(u32x4* __restrict__ YpT) {
    YpT[blockIdx.x * 256u + threadIdx.x] = (u32x4){0, 0, 0, 0};
}

// ---------- fused bilinear -> softmax -> Y, LDS-staged K/V tiles (R7, unchanged) ----------
__global__ __launch_bounds__(256, 2) void attn_kernel(
    const bf16* __restrict__ xb, const bf16* __restrict__ xbT, bf16* __restrict__ YpT)
{
    __shared__ __align__(16) char smem[67584];
    bf16* Ktile = (bf16*)smem;
    bf16* Vtile = (bf16*)(smem + 16384);
    bf16 (*Plds)[32][136] = reinterpret_cast<bf16(*)[32][136]>(smem + 32768);
    bf16 (*Tlds)[132] = reinterpret_cast<bf16(*)[132]>(smem);

    const int tid = threadIdx.x;
    const int w = tid >> 6, l = tid & 63;
    const int lhi = l >> 4, llo = l & 15;
    const uint32_t g = blockIdx.x;
    const int xcd = g & 7, inner = g >> 3;
    const int b = xcd + (inner >> 4) * 8;
    const int cblk = inner & 15;
    const int c0 = cblk * 128 + w * 32;
    const bf16* xbB = xb + (size_t)b * CC * KPAD;
    const bf16* xbTB = xbT + (size_t)b * KPAD * CC;

    bf16x8 aQ[2][2];
#pragma unroll
    for (int cf = 0; cf < 2; cf++)
#pragma unroll
        for (int kk = 0; kk < 2; kk++)
            aQ[cf][kk] = *(const bf16x8*)(xbB + (uint32_t)(c0 + cf * 16 + llo) * KPAD + kk * 32 + lhi * 8);

    const uint32_t rowK = tid >> 3;
    const uint32_t srcKoff = (uint32_t)(((tid & 7u) ^ (rowK & 7u)) << 3);
    const bf16* kSrc = xbB + (size_t)rowK * KPAD + srcKoff;
    const uint32_t rowV = tid >> 4;
    const uint32_t srcVoff = (uint32_t)(((tid & 15u) ^ (rowV & 7u)) << 3);
    const bf16* vSrc = xbTB + (size_t)rowV * CC + srcVoff;

    f32x4 accY[2][4];
#pragma unroll
    for (int cf = 0; cf < 2; cf++)
#pragma unroll
        for (int nf = 0; nf < 4; nf++) accY[cf][nf] = (f32x4){0, 0, 0, 0};
    float rowsum[2][4] = {};

    const float kES = -0.029442756956917622f;

    for (int dt = 0; dt < 16; dt++) {
        const int d0 = dt * 128;
#pragma unroll
        for (int i = 0; i < 4; i++) {
            GLOAD_LDS(kSrc + (size_t)(d0 + i * 32) * KPAD, (char*)Ktile + i * 4096 + tid * 16);
            GLOAD_LDS(vSrc + d0 + (size_t)i * 16 * CC,     (char*)Vtile + i * 4096 + tid * 16);
        }
        __syncthreads();

        f32x4 accS[2][8];
#pragma unroll
        for (int cf = 0; cf < 2; cf++)
#pragma unroll
            for (int df = 0; df < 8; df++) accS[cf][df] = (f32x4){0, 0, 0, 0};
#pragma unroll
        for (int kk = 0; kk < 2; kk++) {
#pragma unroll
            for (int df = 0; df < 8; df++) {
                uint32_t r = (uint32_t)(df * 16 + llo);
                bf16x8 bK = *(const bf16x8*)((const char*)Ktile + r * 128u +
                                             ((((uint32_t)(kk * 4 + lhi)) ^ (r & 7u)) << 4));
                accS[0][df] = MFMA(aQ[0][kk], bK, accS[0][df]);
                accS[1][df] = MFMA(aQ[1][kk], bK, accS[1][df]);
            }
        }
#pragma unroll
        for (int cf = 0; cf < 2; cf++)
#pragma unroll
            for (int df = 0; df < 8; df++)
#pragma unroll
                for (int r = 0; r < 4; r++) {
                    float p = __builtin_amdgcn_exp2f(accS[cf][df][r] * kES);
                    rowsum[cf][r] += p;
                    Plds[w][cf * 16 + lhi * 4 + r][df * 16 + llo] = (bf16)p;
                }
#pragma unroll
        for (int kk2 = 0; kk2 < 4; kk2++) {
            bf16x8 aP[2];
#pragma unroll
            for (int cf = 0; cf < 2; cf++)
                aP[cf] = *(const bf16x8*)&Plds[w][cf * 16 + llo][kk2 * 32 + lhi * 8];
#pragma unroll
            for (int nf = 0; nf < 4; nf++) {
                uint32_t r = (uint32_t)(nf * 16 + llo);
                bf16x8 bV = *(const bf16x8*)((const char*)Vtile + r * 256u +
                                             ((((uint32_t)(kk2 * 4 + lhi)) ^ (r & 7u)) << 4));
                accY[0][nf] = MFMA(aP[0], bV, accY[0][nf]);
                accY[1][nf] = MFMA(aP[1], bV, accY[1][nf]);
            }
        }
        __syncthreads();
    }
#pragma unroll
    for (int cf = 0; cf < 2; cf++)
#pragma unroll
        for (int r = 0; r < 4; r++) {
            float s = rowsum[cf][r];
            s += __shfl_xor(s, 1);
            s += __shfl_xor(s, 2);
            s += __shfl_xor(s, 4);
            s += __shfl_xor(s, 8);
            rowsum[cf][r] = 1.0f / s;
        }
    __syncthreads();
#pragma unroll
    for (int cf = 0; cf < 2; cf++)
#pragma unroll
        for (int nf = 0; nf < 4; nf++)
#pragma unroll
            for (int r = 0; r < 4; r++) {
                int n = nf * 16 + llo;
                int cl = w * 32 + cf * 16 + lhi * 4 + r;
                Tlds[n][cl] = (bf16)(accY[cf][nf][r] * rowsum[cf][r]);
            }
    __syncthreads();
#pragma unroll
    for (int rr = 0; rr < 13; rr++) {
        int row = rr * 4 + (tid >> 6);
        if (row < NPIX) {
            int i = row / 7, j = row % 7;
            int sp = (i + 1) * 9 + (j + 1);
            int col2 = tid & 63;
            uint32_t val = *(const uint32_t*)&Tlds[row][col2 * 2];
            *(uint32_t*)(YpT + ((size_t)b * 81 + sp) * CC + cblk * 128 + col2 * 2) = val;
        }
    }
}

// ---------- conv GEMM: 256x256, BK=64, per-phase counted-vmcnt pipeline (T3+T4) ----------
// LDS per buffer: A.k0 @+0, A.k1 @+16384, B.k0 @+32768, B.k1 @+49152 (sub-tile rows 64B,
// read-swizzle slot^= (row>>1)&3, source pre-swizzled to match). buf0 @0, buf1 @65536.
// Phase = vmcnt(8) -> barrier -> stage 1 half (4 loads) -> 12 ds_read -> 32 MFMA.
// Each staged half has 2 full phases of latency cover; gates uniform vmcnt(8),
// epilogue peeled with (8,8,4,0).
#define CONV_BARRIER() do { __builtin_amdgcn_sched_barrier(0); \
    __builtin_amdgcn_s_barrier(); __builtin_amdgcn_sched_barrier(0); } while (0)
#define CONV_VMW(n) asm volatile("s_waitcnt vmcnt(" #n ")" ::: "memory")

#define STAGE_HALF(bufOff, t, kh) do {                                         \
    uint32_t kt_ = z * 72u + (uint32_t)(t);                                    \
    uint32_t tap_ = kt_ >> 5, ci0_ = (kt_ & 31u) << 6;                         \
    int tapoff_ = (int)(tap_ / 3u) * 9 + (int)(tap_ % 3u) - 10;                \
    uint32_t kA_ = (uint32_t)(t) * 64u + (uint32_t)(kh) * 32u;                 \
    _Pragma("unroll")                                                          \
    for (int i_ = 0; i_ < 2; i_++) {                                           \
        GLOAD_LDS(srcA[i_] + kA_,                                              \
                  smem + (bufOff) + (kh) * 16384 + i_ * 8192 + tid * 16);      \
        GLOAD_LDS(srcB[i_] + (int)(ci0_ + (uint32_t)(kh) * 32u) + tapoff_ * 2048, \
                  smem + (bufOff) + 32768 + (kh) * 16384 + i_ * 8192 + tid * 16); \
    }                                                                          \
} while (0)

#define CONV_PHASE(bufOff, kk, GATE, STAGE_STMT) do {                          \
    CONV_VMW(GATE);                                                            \
    CONV_BARRIER();                                                            \
    STAGE_STMT;                                                                \
    bf16x8 af[8], bfr[4];                                                      \
    _Pragma("unroll")                                                          \
    for (int f = 0; f < 8; f++)                                                \
        af[f] = *(const bf16x8*)(smem + (bufOff) + (kk) * 16384 + offA[f]);    \
    _Pragma("unroll")                                                          \
    for (int f = 0; f < 4; f++)                                                \
        bfr[f] = *(const bf16x8*)(smem + (bufOff) + 32768 + (kk) * 16384 + offB[f]); \
    __builtin_amdgcn_s_setprio(1);                                             \
    _Pragma("unroll")                                                          \
    for (int fm = 0; fm < 8; fm++)                                             \
        _Pragma("unroll")                                                      \
        for (int fn = 0; fn < 4; fn++)                                         \
            acc[fm][fn] = MFMA(af[fm], bfr[fn], acc[fm][fn]);                  \
    __builtin_amdgcn_s_setprio(0);                                             \
    __builtin_amdgcn_sched_barrier(0);                                         \
} while (0)

__global__ __launch_bounds__(512, 2) void conv_kernel(
    const bf16* __restrict__ Wr, const bf16* __restrict__ YpT, float* __restrict__ partials)
{
    extern __shared__ __align__(16) char smem[];
    const int tid = threadIdx.x;
    const int w = tid >> 6, l = tid & 63;
    const int lhi = l >> 4, llo = l & 15;
    const int wm = w >> 2, wn = w & 3;           // wave owns 128co x 64n

    uint32_t g = blockIdx.x;
    uint32_t xcd = g & 7u, inner = g >> 3;       // inner in [0,28)
    uint32_t pairIdx = xcd * 4u + inner / 7u;    // [0,32): (z,mt) grouped per XCD
    uint32_t nt = inner % 7u;
    uint32_t z = pairIdx >> 3, mt = pairIdx & 7u;

    // staging source (pre-swizzled to match read swizzle slot ^ ((row>>1)&3))
    uint32_t rowLoc = tid >> 2;                  // [0,128)
    uint32_t slot = tid & 3u;
    const bf16* srcA[2];
    const bf16* srcB[2];
#pragma unroll
    for (int i = 0; i < 2; i++) {
        uint32_t row = (uint32_t)i * 128u + rowLoc;
        uint32_t swz = (uint32_t)((slot ^ ((row >> 1) & 3u)) << 3);
        srcA[i] = Wr + (size_t)(mt * 256u + row) * K9 + (size_t)z * 4608u + swz;
        uint32_t n = nt * 256u + row;
        uint32_t rowIdx;
        if (n < 1568u) {
            uint32_t b = n / 49u, p = n % 49u;
            uint32_t i2 = p / 7u, j2 = p % 7u;
            rowIdx = b * 81u + (i2 + 1u) * 9u + (j2 + 1u);
        } else rowIdx = 2602u;
        srcB[i] = YpT + (size_t)rowIdx * 2048u + swz;
    }

    // ds_read fragment offsets (swizzled, loop-invariant)
    uint32_t offA[8], offB[4];
#pragma unroll
    for (int f = 0; f < 8; f++) {
        uint32_t r = (uint32_t)(wm * 128 + f * 16 + llo);
        offA[f] = r * 64u + (uint32_t)(((uint32_t)lhi ^ ((r >> 1) & 3u)) << 4);
    }
#pragma unroll
    for (int f = 0; f < 4; f++) {
        uint32_t r = (uint32_t)(wn * 64 + f * 16 + llo);
        offB[f] = r * 64u + (uint32_t)(((uint32_t)lhi ^ ((r >> 1) & 3u)) << 4);
    }

    f32x4 acc[8][4];
#pragma unroll
    for (int fm = 0; fm < 8; fm++)
#pragma unroll
        for (int fn = 0; fn < 4; fn++) acc[fm][fn] = (f32x4){0, 0, 0, 0};

    // prologue: T0.k0, T0.k1 -> buf0; T1.k0 -> buf1   (12 loads/thread)
    STAGE_HALF(0, 0, 0);
    STAGE_HALF(0, 0, 1);
    STAGE_HALF(65536, 1, 0);

    for (int it = 0; it < 35; ++it) {
        const int t0 = it * 2;
        CONV_PHASE(0,     0, 8, STAGE_HALF(65536, t0 + 1, 1));
        CONV_PHASE(0,     1, 8, STAGE_HALF(0,     t0 + 2, 0));
        CONV_PHASE(65536, 0, 8, STAGE_HALF(0,     t0 + 2, 1));
        CONV_PHASE(65536, 1, 8, STAGE_HALF(65536, t0 + 3, 0));
    }
    // peeled final iteration (T70 buf0, T71 buf1)
    CONV_PHASE(0,     0, 8, STAGE_HALF(65536, 71, 1));
    CONV_PHASE(0,     1, 8, (void)0);
    CONV_PHASE(65536, 0, 4, (void)0);
    CONV_PHASE(65536, 1, 0, (void)0);

    float* pz = partials + (size_t)z * 2048u * NP;
    uint32_t co0 = mt * 256u + (uint32_t)(wm * 128 + lhi * 4);
    uint32_t n0 = nt * 256u + (uint32_t)(wn * 64 + llo);
#pragma unroll
    for (int fm = 0; fm < 8; fm++)
#pragma unroll
        for (int fn = 0; fn < 4; fn++)
#pragma unroll
            for (int r = 0; r < 4; r++)
                pz[(size_t)(co0 + fm * 16u + r) * NP + (n0 + fn * 16u)] = acc[fm][fn][r];
}

// ---------- reduce: out = sum_z partials + bias + residual ----------
__global__ void reduce_kernel(const float* __restrict__ partials, const float* __restrict__ x,
                              const float* __restrict__ cb, float* __restrict__ out)
{
    uint32_t idx = blockIdx.x * 256u + threadIdx.x;
    uint32_t p = idx % 49u;
    uint32_t c = (idx / 49u) & 2047u;
    uint32_t b = idx / (49u * 2048u);
    uint32_t n = b * 49u + p;
    size_t base = (size_t)c * NP + n;
    float s = cb[c] + x[idx];
#pragma unroll
    for (int zz = 0; zz < CONV_SPLITK; zz++) s += partials[(size_t)zz * 2048u * NP + base];
    out[idx] = s;
}

extern "C" void kernel_launch(void* const* d_in, const int* in_sizes, int n_in,
                              void* d_out, int out_size, void* d_ws, size_t ws_size,
                              hipStream_t stream) {
    (void)in_sizes; (void)n_in; (void)out_size; (void)ws_size;
    const float* x = (const float*)d_in[0];
    const float* cw = (const float*)d_in[1];
    const float* cb = (const float*)d_in[2];
    float* out = (float*)d_out;
    char* ws = (char*)d_ws;

    bf16* xb   = (bf16*)(ws);                    //   8,388,608 B
    bf16* xbT  = (bf16*)(ws + 8388608);          //   8,388,608 B
    bf16* Wr   = (bf16*)(ws + 16777216);         //  75,497,472 B
    bf16* YpT  = (bf16*)(ws + 92274688);         //  10,747,904 B
    float* partials = (float*)(ws + 103022592);  //  58,720,256 B (total 161,742,848)

    hipFuncSetAttribute((const void*)conv_kernel,
                        hipFuncAttributeMaxDynamicSharedMemorySize, 131072);

    prep_fused_kernel<<<512, 256, 0, stream>>>(x, xb, xbT);
    castw_kernel<<<4096, 256, 0, stream>>>(cw, Wr);
    zero_ypt_kernel<<<2624, 256, 0, stream>>>((u32x4*)YpT);
    attn_kernel<<<512, 256, 0, stream>>>(xb, xbT, YpT);
    conv_kernel<<<224, 512, 131072, stream>>>(Wr, YpT, partials);
    reduce_kernel<<<12544, 256, 0, stream>>>(partials, x, cb, out);
}

// Round 11
// 237.905 us; speedup vs baseline: 1.1901x; 1.0210x over previous
//
#include <hip/hip_runtime.h>
#include <stdint.h>

#define BB 32
#define CC 2048
#define NPIX 49
#define KPAD 64
#define K9 18432      // CC*9 (k = tap*2048 + ci, tap-major)
#define ZROWS 2624    // 32*81 interior+halo rows + 32 guard rows (zero)
#define NP 1792       // dense n padded (14*128)
#define CONV_SPLITK 4

typedef __bf16 bf16;
typedef __bf16 bf16x2 __attribute__((ext_vector_type(2)));
typedef __bf16 bf16x4 __attribute__((ext_vector_type(4)));
typedef __bf16 bf16x8 __attribute__((ext_vector_type(8)));
typedef float f32x4 __attribute__((ext_vector_type(4)));
typedef uint32_t u32x4 __attribute__((ext_vector_type(4)));

#define MFMA(a,b,c) __builtin_amdgcn_mfma_f32_16x16x32_bf16(a,b,c,0,0,0)
#define GLOAD_LDS(g, l) __builtin_amdgcn_global_load_lds( \
    (const __attribute__((address_space(1))) void*)(g),   \
    (__attribute__((address_space(3))) void*)(l), 16, 0, 0)

// ---------- fused prep: x -> xb [B][C][64] AND xbT [B][64][C] (reads x once) ----------
__global__ void prep_fused_kernel(const float* __restrict__ x,
                                  bf16* __restrict__ xb, bf16* __restrict__ xbT) {
    __shared__ float xt[6272];   // 128*49
    const int tid = threadIdx.x;
    const int b = blockIdx.x >> 4, cb = blockIdx.x & 15;
    const float* src = x + ((size_t)(b * 2048 + cb * 128)) * 49;
#pragma unroll
    for (int i = 0; i < 25; i++) {
        int idx = i * 256 + tid;
        if (idx < 6272) xt[idx] = src[idx];
    }
    __syncthreads();
    {
        const int r = tid >> 1, h = tid & 1;
        bf16* dst = xb + ((size_t)(b * 2048 + cb * 128 + r)) * 64 + h * 32;
        const float* row = &xt[r * 49];
#pragma unroll
        for (int v = 0; v < 4; v++) {
            bf16x8 o;
#pragma unroll
            for (int e = 0; e < 8; e++) {
                int n = h * 32 + v * 8 + e;
                o[e] = (bf16)(n < 49 ? row[n] : 0.f);
            }
            *(bf16x8*)(dst + v * 8) = o;
        }
    }
    {
        const int n = tid >> 2, q = tid & 3;
        bf16* dst = xbT + ((size_t)b * 64 + n) * 2048 + cb * 128 + q * 32;
#pragma unroll
        for (int v = 0; v < 4; v++) {
            bf16x8 o;
#pragma unroll
            for (int e = 0; e < 8; e++) {
                int cl = q * 32 + v * 8 + e;
                o[e] = (bf16)(n < 49 ? xt[cl * 49 + n] : 0.f);
            }
            *(bf16x8*)(dst + v * 8) = o;
        }
    }
}

// ---------- prep: conv_w [co][ci][3][3] f32 -> Wr [co][t][ci] bf16 ----------
__global__ void castw_kernel(const float* __restrict__ cw, bf16* __restrict__ Wr) {
    uint32_t t = blockIdx.x * 256u + threadIdx.x;
    uint32_t q = t & 511u, co = t >> 9;
    uint32_t ci0 = q * 4u;
    const float* src = cw + ((size_t)co * 2048u + ci0) * 9u;
    float v[4][9];
#pragma unroll
    for (int c = 0; c < 4; c++)
#pragma unroll
        for (int tt = 0; tt < 9; tt++) v[c][tt] = src[c * 9 + tt];
    bf16* dst = Wr + (size_t)co * K9 + ci0;
#pragma unroll
    for (int tt = 0; tt < 9; tt++) {
        bf16x4 o;
        o[0] = (bf16)v[0][tt]; o[1] = (bf16)v[1][tt];
        o[2] = (bf16)v[2][tt]; o[3] = (bf16)v[3][tt];
        *(bf16x4*)(dst + (size_t)tt * 2048u) = o;
    }
}

// ---------- prep: zero YpT ----------
__global__ void zero_ypt_kernel(u32x4* __restrict__ YpT) {
    YpT[blockIdx.x * 256u + threadIdx.x] = (u32x4){0, 0, 0, 0};
}

// ---------- fused bilinear -> softmax -> Y: 8 waves x 16 c-rows (2x TLP vs R7) ----------
// 512 blocks (4 batches/XCD), 512 threads. Per dt: stage Ktile[128][64] + Vtile[64][128]
// via global_load_lds; T2 both-sides XOR swizzle on fragment reads; Plds wave-private.
__global__ __launch_bounds__(512, 2) void attn_kernel(
    const bf16* __restrict__ xb, const bf16* __restrict__ xbT, bf16* __restrict__ YpT)
{
    __shared__ __align__(16) char smem[67584];
    bf16* Ktile = (bf16*)smem;                         // [128 d][64 k]   swizzled
    bf16* Vtile = (bf16*)(smem + 16384);               // [64 n][128 d]   swizzled
    bf16 (*Plds)[16][136] = reinterpret_cast<bf16(*)[16][136]>(smem + 32768);  // [8 w][16][136]
    bf16 (*Tlds)[132] = reinterpret_cast<bf16(*)[132]>(smem);  // epilogue alias

    const int tid = threadIdx.x;
    const int w = tid >> 6, l = tid & 63;
    const int lhi = l >> 4, llo = l & 15;
    const uint32_t g = blockIdx.x;
    const int xcd = g & 7, inner = g >> 3;
    const int b = xcd + (inner >> 4) * 8;              // 4 batches per XCD
    const int cblk = inner & 15;
    const int c0 = cblk * 128 + w * 16;                // wave owns 16 c-rows
    const bf16* xbB = xb + (size_t)b * CC * KPAD;
    const bf16* xbTB = xbT + (size_t)b * KPAD * CC;

    bf16x8 aQ[2];
#pragma unroll
    for (int kk = 0; kk < 2; kk++)
        aQ[kk] = *(const bf16x8*)(xbB + (uint32_t)(c0 + llo) * KPAD + kk * 32 + lhi * 8);

    // staging geometry: K 2 iters x 64 rows, V 2 iters x 32 rows (512 thr x 16B)
    const uint32_t rowK = tid >> 3;                    // [0,64)
    const uint32_t srcKoff = (uint32_t)(((tid & 7u) ^ (rowK & 7u)) << 3);
    const bf16* kSrc = xbB + (size_t)rowK * KPAD + srcKoff;
    const uint32_t rowV = tid >> 4;                    // [0,32)
    const uint32_t srcVoff = (uint32_t)(((tid & 15u) ^ (rowV & 7u)) << 3);
    const bf16* vSrc = xbTB + (size_t)rowV * CC + srcVoff;

    f32x4 accY[4];
#pragma unroll
    for (int nf = 0; nf < 4; nf++) accY[nf] = (f32x4){0, 0, 0, 0};
    float rowsum[4] = {};

    const float kES = -0.029442756956917622f;          // -log2(e)/49

    for (int dt = 0; dt < 16; dt++) {
        const int d0 = dt * 128;
#pragma unroll
        for (int i = 0; i < 2; i++) {
            GLOAD_LDS(kSrc + (size_t)(d0 + i * 64) * KPAD, (char*)Ktile + i * 8192 + tid * 16);
            GLOAD_LDS(vSrc + d0 + (size_t)i * 32 * CC,     (char*)Vtile + i * 8192 + tid * 16);
        }
        __syncthreads();

        f32x4 accS[8];
#pragma unroll
        for (int df = 0; df < 8; df++) accS[df] = (f32x4){0, 0, 0, 0};
#pragma unroll
        for (int kk = 0; kk < 2; kk++) {
#pragma unroll
            for (int df = 0; df < 8; df++) {
                uint32_t r = (uint32_t)(df * 16 + llo);
                bf16x8 bK = *(const bf16x8*)((const char*)Ktile + r * 128u +
                                             ((((uint32_t)(kk * 4 + lhi)) ^ (r & 7u)) << 4));
                accS[df] = MFMA(aQ[kk], bK, accS[df]);
            }
        }
#pragma unroll
        for (int df = 0; df < 8; df++)
#pragma unroll
            for (int r = 0; r < 4; r++) {
                float p = __builtin_amdgcn_exp2f(accS[df][r] * kES);
                rowsum[r] += p;
                Plds[w][lhi * 4 + r][df * 16 + llo] = (bf16)p;
            }
        // Plds is wave-private: compiler-ordered via lgkmcnt, no barrier
#pragma unroll
        for (int kk2 = 0; kk2 < 4; kk2++) {
            bf16x8 aP = *(const bf16x8*)&Plds[w][llo][kk2 * 32 + lhi * 8];
#pragma unroll
            for (int nf = 0; nf < 4; nf++) {
                uint32_t r = (uint32_t)(nf * 16 + llo);
                bf16x8 bV = *(const bf16x8*)((const char*)Vtile + r * 256u +
                                             ((((uint32_t)(kk2 * 4 + lhi)) ^ (r & 7u)) << 4));
                accY[nf] = MFMA(aP, bV, accY[nf]);
            }
        }
        __syncthreads();
    }
#pragma unroll
    for (int r = 0; r < 4; r++) {
        float s = rowsum[r];
        s += __shfl_xor(s, 1);
        s += __shfl_xor(s, 2);
        s += __shfl_xor(s, 4);
        s += __shfl_xor(s, 8);
        rowsum[r] = 1.0f / s;
    }
    __syncthreads();   // Tlds aliases K/V tiles
#pragma unroll
    for (int nf = 0; nf < 4; nf++)
#pragma unroll
        for (int r = 0; r < 4; r++) {
            int n = nf * 16 + llo;
            int cl = w * 16 + lhi * 4 + r;
            Tlds[n][cl] = (bf16)(accY[nf][r] * rowsum[r]);
        }
    __syncthreads();
#pragma unroll
    for (int rr = 0; rr < 7; rr++) {
        int row = rr * 8 + w;
        if (row < NPIX) {
            int i = row / 7, j = row % 7;
            int sp = (i + 1) * 9 + (j + 1);
            int col2 = tid & 63;
            uint32_t val = *(const uint32_t*)&Tlds[row][col2 * 2];
            *(uint32_t*)(YpT + ((size_t)b * 81 + sp) * CC + cblk * 128 + col2 * 2) = val;
        }
    }
}

// ---------- conv GEMM: 256x256, BK=64, per-phase counted-vmcnt pipeline ----------
// R10 ledger/gates unchanged; phase interior = m201: reads -> stage -> lgkmcnt(0) pin
// -> sched_barrier -> setprio MFMA cluster (T5 role-split).
#define CONV_BARRIER() do { __builtin_amdgcn_sched_barrier(0); \
    __builtin_amdgcn_s_barrier(); __builtin_amdgcn_sched_barrier(0); } while (0)
#define CONV_VMW(n) asm volatile("s_waitcnt vmcnt(" #n ")" ::: "memory")

#define STAGE_HALF(bufOff, t, kh) do {                                         \
    uint32_t kt_ = z * 72u + (uint32_t)(t);                                    \
    uint32_t tap_ = kt_ >> 5, ci0_ = (kt_ & 31u) << 6;                         \
    int tapoff_ = (int)(tap_ / 3u) * 9 + (int)(tap_ % 3u) - 10;                \
    uint32_t kA_ = (uint32_t)(t) * 64u + (uint32_t)(kh) * 32u;                 \
    _Pragma("unroll")                                                          \
    for (int i_ = 0; i_ < 2; i_++) {                                           \
        GLOAD_LDS(srcA[i_] + kA_,                                              \
                  smem + (bufOff) + (kh) * 16384 + i_ * 8192 + tid * 16);      \
        GLOAD_LDS(srcB[i_] + (int)(ci0_ + (uint32_t)(kh) * 32u) + tapoff_ * 2048, \
                  smem + (bufOff) + 32768 + (kh) * 16384 + i_ * 8192 + tid * 16); \
    }                                                                          \
} while (0)

#define CONV_PHASE(bufOff, kk, GATE, STAGE_STMT) do {                          \
    CONV_VMW(GATE);                                                            \
    CONV_BARRIER();                                                            \
    bf16x8 af[8], bfr[4];                                                      \
    _Pragma("unroll")                                                          \
    for (int f = 0; f < 8; f++)                                                \
        af[f] = *(const bf16x8*)(smem + (bufOff) + (kk) * 16384 + offA[f]);    \
    _Pragma("unroll")                                                          \
    for (int f = 0; f < 4; f++)                                                \
        bfr[f] = *(const bf16x8*)(smem + (bufOff) + 32768 + (kk) * 16384 + offB[f]); \
    STAGE_STMT;                                                                \
    asm volatile("s_waitcnt lgkmcnt(0)" ::: "memory");                         \
    __builtin_amdgcn_sched_barrier(0);                                         \
    __builtin_amdgcn_s_setprio(1);                                             \
    _Pragma("unroll")                                                          \
    for (int fm = 0; fm < 8; fm++)                                             \
        _Pragma("unroll")                                                      \
        for (int fn = 0; fn < 4; fn++)                                         \
            acc[fm][fn] = MFMA(af[fm], bfr[fn], acc[fm][fn]);                  \
    __builtin_amdgcn_s_setprio(0);                                             \
    __builtin_amdgcn_sched_barrier(0);                                         \
} while (0)

__global__ __launch_bounds__(512, 2) void conv_kernel(
    const bf16* __restrict__ Wr, const bf16* __restrict__ YpT, float* __restrict__ partials)
{
    extern __shared__ __align__(16) char smem[];
    const int tid = threadIdx.x;
    const int w = tid >> 6, l = tid & 63;
    const int lhi = l >> 4, llo = l & 15;
    const int wm = w >> 2, wn = w & 3;           // wave owns 128co x 64n

    uint32_t g = blockIdx.x;
    uint32_t xcd = g & 7u, inner = g >> 3;       // inner in [0,28)
    uint32_t pairIdx = xcd * 4u + inner / 7u;    // [0,32): (z,mt) grouped per XCD
    uint32_t nt = inner % 7u;
    uint32_t z = pairIdx >> 3, mt = pairIdx & 7u;

    // staging source (pre-swizzled to match read swizzle slot ^ ((row>>1)&3))
    uint32_t rowLoc = tid >> 2;                  // [0,128)
    uint32_t slot = tid & 3u;
    const bf16* srcA[2];
    const bf16* srcB[2];
#pragma unroll
    for (int i = 0; i < 2; i++) {
        uint32_t row = (uint32_t)i * 128u + rowLoc;
        uint32_t swz = (uint32_t)((slot ^ ((row >> 1) & 3u)) << 3);
        srcA[i] = Wr + (size_t)(mt * 256u + row) * K9 + (size_t)z * 4608u + swz;
        uint32_t n = nt * 256u + row;
        uint32_t rowIdx;
        if (n < 1568u) {
            uint32_t b = n / 49u, p = n % 49u;
            uint32_t i2 = p / 7u, j2 = p % 7u;
            rowIdx = b * 81u + (i2 + 1u) * 9u + (j2 + 1u);
        } else rowIdx = 2602u;
        srcB[i] = YpT + (size_t)rowIdx * 2048u + swz;
    }

    // ds_read fragment offsets (swizzled, loop-invariant)
    uint32_t offA[8], offB[4];
#pragma unroll
    for (int f = 0; f < 8; f++) {
        uint32_t r = (uint32_t)(wm * 128 + f * 16 + llo);
        offA[f] = r * 64u + (uint32_t)(((uint32_t)lhi ^ ((r >> 1) & 3u)) << 4);
    }
#pragma unroll
    for (int f = 0; f < 4; f++) {
        uint32_t r = (uint32_t)(wn * 64 + f * 16 + llo);
        offB[f] = r * 64u + (uint32_t)(((uint32_t)lhi ^ ((r >> 1) & 3u)) << 4);
    }

    f32x4 acc[8][4];
#pragma unroll
    for (int fm = 0; fm < 8; fm++)
#pragma unroll
        for (int fn = 0; fn < 4; fn++) acc[fm][fn] = (f32x4){0, 0, 0, 0};

    // prologue: T0.k0, T0.k1 -> buf0; T1.k0 -> buf1   (12 loads/thread)
    STAGE_HALF(0, 0, 0);
    STAGE_HALF(0, 0, 1);
    STAGE_HALF(65536, 1, 0);

    for (int it = 0; it < 35; ++it) {
        const int t0 = it * 2;
        CONV_PHASE(0,     0, 8, STAGE_HALF(65536, t0 + 1, 1));
        CONV_PHASE(0,     1, 8, STAGE_HALF(0,     t0 + 2, 0));
        CONV_PHASE(65536, 0, 8, STAGE_HALF(0,     t0 + 2, 1));
        CONV_PHASE(65536, 1, 8, STAGE_HALF(65536, t0 + 3, 0));
    }
    // peeled final iteration (T70 buf0, T71 buf1)
    CONV_PHASE(0,     0, 8, STAGE_HALF(65536, 71, 1));
    CONV_PHASE(0,     1, 8, (void)0);
    CONV_PHASE(65536, 0, 4, (void)0);
    CONV_PHASE(65536, 1, 0, (void)0);

    float* pz = partials + (size_t)z * 2048u * NP;
    uint32_t co0 = mt * 256u + (uint32_t)(wm * 128 + lhi * 4);
    uint32_t n0 = nt * 256u + (uint32_t)(wn * 64 + llo);
#pragma unroll
    for (int fm = 0; fm < 8; fm++)
#pragma unroll
        for (int fn = 0; fn < 4; fn++)
#pragma unroll
            for (int r = 0; r < 4; r++)
                pz[(size_t)(co0 + fm * 16u + r) * NP + (n0 + fn * 16u)] = acc[fm][fn][r];
}

// ---------- reduce: out = sum_z partials + bias + residual ----------
__global__ void reduce_kernel(const float* __restrict__ partials, const float* __restrict__ x,
                              const float* __restrict__ cb, float* __restrict__ out)
{
    uint32_t idx = blockIdx.x * 256u + threadIdx.x;
    uint32_t p = idx % 49u;
    uint32_t c = (idx / 49u) & 2047u;
    uint32_t b = idx / (49u * 2048u);
    uint32_t n = b * 49u + p;
    size_t base = (size_t)c * NP + n;
    float s = cb[c] + x[idx];
#pragma unroll
    for (int zz = 0; zz < CONV_SPLITK; zz++) s += partials[(size_t)zz * 2048u * NP + base];
    out[idx] = s;
}

extern "C" void kernel_launch(void* const* d_in, const int* in_sizes, int n_in,
                              void* d_out, int out_size, void* d_ws, size_t ws_size,
                              hipStream_t stream) {
    (void)in_sizes; (void)n_in; (void)out_size; (void)ws_size;
    const float* x = (const float*)d_in[0];
    const float* cw = (const float*)d_in[1];
    const float* cb = (const float*)d_in[2];
    float* out = (float*)d_out;
    char* ws = (char*)d_ws;

    bf16* xb   = (bf16*)(ws);                    //   8,388,608 B
    bf16* xbT  = (bf16*)(ws + 8388608);          //   8,388,608 B
    bf16* Wr   = (bf16*)(ws + 16777216);         //  75,497,472 B
    bf16* YpT  = (bf16*)(ws + 92274688);         //  10,747,904 B
    float* partials = (float*)(ws + 103022592);  //  58,720,256 B (total 161,742,848)

    hipFuncSetAttribute((const void*)conv_kernel,
                        hipFuncAttributeMaxDynamicSharedMemorySize, 131072);

    prep_fused_kernel<<<512, 256, 0, stream>>>(x, xb, xbT);
    castw_kernel<<<4096, 256, 0, stream>>>(cw, Wr);
    zero_ypt_kernel<<<2624, 256, 0, stream>>>((u32x4*)YpT);
    attn_kernel<<<512, 512, 0, stream>>>(xb, xbT, YpT);
    conv_kernel<<<224, 512, 131072, stream>>>(Wr, YpT, partials);
    reduce_kernel<<<12544, 256, 0, stream>>>(partials, x, cb, out);
}